// Round 1
// baseline (189.628 us; speedup 1.0000x reference)
//
#include <hip/hip_runtime.h>
#include <math.h>

#define NA_ 10000
#define NM_ 150000
#define B_  4
#define NS_ 4
#define NMAX_ 32
#define NO_ 4
#define H1_ 4
#define H2_ 38
#define PI_F 3.14159265358979323846f

// ---------------------------------------------------------------------------
// Kernel 0: segment starts from sorted iidx. starts[b][a] = first pair index p
// with iidx[b][p] >= a ; starts[b][NA] = NM.
// ---------------------------------------------------------------------------
__global__ void starts_kernel(const int* __restrict__ iidx, int* __restrict__ starts) {
    int p = blockIdx.x * blockDim.x + threadIdx.x;
    if (p >= B_ * NM_) return;
    int b = p / NM_, pl = p - b * NM_;
    const int* ii = iidx + (size_t)b * NM_;
    int* st = starts + (size_t)b * (NA_ + 1);
    int cur = ii[pl];
    int prev = (pl == 0) ? -1 : ii[pl - 1];
    for (int a = prev + 1; a <= cur; ++a) st[a] = pl;
    if (pl == NM_ - 1) {
        for (int a = cur + 1; a <= NA_; ++a) st[a] = NM_;
    }
}

// ---------------------------------------------------------------------------
// Main pass kernel: one wave (64 lanes) per (image, atom).
// Lane layout: h = lane>>5 (owns l = 2h and 2h+1), n = lane&31.
// PASS=0: density with species_params as Csn, then MLP -> write Csn2.
// PASS=1: density with Csn2, write rho to out.
// ---------------------------------------------------------------------------
template <int PASS>
__global__ __launch_bounds__(256) void pass_kernel(
    const float* __restrict__ disp, const float* __restrict__ alpha,
    const float* __restrict__ rsp, const float* __restrict__ spp,
    const float* __restrict__ op, const float* __restrict__ w1,
    const float* __restrict__ b1, const float* __restrict__ w2,
    const float* __restrict__ b2, const float* __restrict__ w3,
    const float* __restrict__ b3, const int* __restrict__ jidx,
    const int* __restrict__ sorted_numbers, const int* __restrict__ starts,
    float* __restrict__ csn2, float* __restrict__ out)
{
    int wave = blockIdx.x * 4 + (threadIdx.x >> 6);
    if (wave >= B_ * NA_) return;
    int b = wave / NA_, a = wave - b * NA_;
    int lane = threadIdx.x & 63;
    int h = lane >> 5;
    int n = lane & 31;

    // per-species per-n tables into registers
    float al[NS_], rv[NS_], spv[NS_];
#pragma unroll
    for (int s = 0; s < NS_; ++s) {
        al[s]  = alpha[s * NMAX_ + n];
        rv[s]  = rsp[s * NMAX_ + n];
        spv[s] = spp[s * NMAX_ + n];
    }

    // W[l][n][o] for this lane's two l values.
    // op shape (2,2,NMAX,NO); W[l] = op[PASS][ l==0 ? 0 : 1 ]
    const float* opb = op + (size_t)PASS * 2 * NMAX_ * NO_;
    const int i0 = (h == 0) ? 0 : 1;  // l = 2h
    const int i1 = 1;                 // l = 2h+1
    float W0[NO_], W1[NO_];
#pragma unroll
    for (int o = 0; o < NO_; ++o) {
        W0[o] = opb[(i0 * NMAX_ + n) * NO_ + o];
        W1[o] = opb[(i1 * NMAX_ + n) * NO_ + o];
    }

    const int* st = starts + (size_t)b * (NA_ + 1);
    int p0 = st[a], p1 = st[a + 1];
    const int* jj = jidx + (size_t)b * NM_;
    const float* dp = disp + (size_t)b * NM_ * 3;

    float acc0 = 0.f, acc1 = 0.f;  // bnl[2h][n], bnl[2h+1][n]
    for (int p = p0; p < p1; ++p) {
        int j = jj[p];
        float x = dp[(size_t)p * 3 + 0];
        float y = dp[(size_t)p * 3 + 1];
        float z = dp[(size_t)p * 3 + 2];
        float dist = sqrtf(x * x + y * y + z * z);
        float c = __cosf(dist * (PI_F / 6.0f));
        float fc = 0.25f * (c + 1.f) * (c + 1.f);
        int jat = sorted_numbers[j];
        float av  = (jat == 0) ? al[0] : (jat == 1) ? al[1] : (jat == 2) ? al[2] : al[3];
        float rsv = (jat == 0) ? rv[0] : (jat == 1) ? rv[1] : (jat == 2) ? rv[2] : rv[3];
        float dd = dist - rsv;
        float rad = __expf(av * dd * dd);
        float cj;
        if constexpr (PASS == 0) {
            cj = (jat == 0) ? spv[0] : (jat == 1) ? spv[1] : (jat == 2) ? spv[2] : spv[3];
        } else {
            cj = csn2[((size_t)(b * NA_ + j)) * NMAX_ + n];
        }
        float coef = fc * rad * cj;
        float a0 = (h == 0) ? 1.0f : y;  // angle for l=2h   (l=0 -> 1, l=2 -> y)
        float a1 = (h == 0) ? x : z;     // angle for l=2h+1 (l=1 -> x, l=3 -> z)
        acc0 = fmaf(coef, a0, acc0);
        acc1 = fmaf(coef, a1, acc1);
    }

    // t[l][o] = sum_n W[l][n][o] * bnl[l][n] : reduce over 32 lanes within half
    float t0[NO_], t1[NO_];
#pragma unroll
    for (int o = 0; o < NO_; ++o) { t0[o] = W0[o] * acc0; t1[o] = W1[o] * acc1; }
#pragma unroll
    for (int off = 1; off < 32; off <<= 1) {
#pragma unroll
        for (int o = 0; o < NO_; ++o) {
            t0[o] += __shfl_xor(t0[o], off);
            t1[o] += __shfl_xor(t1[o], off);
        }
    }
    // rho[o] = sum_l t[l][o]^2  (combine two halves)
    float rho[NO_];
#pragma unroll
    for (int o = 0; o < NO_; ++o) rho[o] = t0[o] * t0[o] + t1[o] * t1[o];
#pragma unroll
    for (int o = 0; o < NO_; ++o) rho[o] += __shfl_xor(rho[o], 32);

    if constexpr (PASS == 1) {
        if (lane == 0) {
            float4 r4 = make_float4(rho[0], rho[1], rho[2], rho[3]);
            *reinterpret_cast<float4*>(out + ((size_t)(b * NA_ + a)) * NO_) = r4;
        }
        return;
    } else {
        // MLP: h1 = tanh(rho @ w1 + b1)  (all lanes, redundant)
        float h1v[H1_];
#pragma unroll
        for (int k = 0; k < H1_; ++k) {
            float s = b1[k];
#pragma unroll
            for (int o = 0; o < NO_; ++o) s = fmaf(rho[o], w1[o * H1_ + k], s);
            h1v[k] = tanhf(s);
        }
        // h2[j] on lane j (j<38); lanes >=38 compute garbage (clamped, unused)
        int jc = (lane < H2_) ? lane : (H2_ - 1);
        float s2 = b2[jc];
#pragma unroll
        for (int k = 0; k < H1_; ++k) s2 = fmaf(h1v[k], w2[k * H2_ + jc], s2);
        float hv = tanhf(s2);
        // out[n] = b3[n] + sum_j h2[j]*w3[j][n]
        float on = b3[n];
#pragma unroll
        for (int j2 = 0; j2 < H2_; ++j2) {
            float hj = __shfl(hv, j2);
            on = fmaf(hj, w3[j2 * NMAX_ + n], on);
        }
        int aat = sorted_numbers[a];
        float base = (aat == 0) ? spv[0] : (aat == 1) ? spv[1] : (aat == 2) ? spv[2] : spv[3];
        if (lane < 32) {
            csn2[((size_t)(b * NA_ + a)) * NMAX_ + n] = base + on;
        }
    }
}

extern "C" void kernel_launch(void* const* d_in, const int* in_sizes, int n_in,
                              void* d_out, int out_size, void* d_ws, size_t ws_size,
                              hipStream_t stream) {
    const float* disp = (const float*)d_in[0];
    const float* alpha = (const float*)d_in[1];
    const float* rsp = (const float*)d_in[2];
    const float* spp = (const float*)d_in[3];
    const float* op = (const float*)d_in[4];
    const float* w1 = (const float*)d_in[5];
    const float* b1 = (const float*)d_in[6];
    const float* w2 = (const float*)d_in[7];
    const float* b2 = (const float*)d_in[8];
    const float* w3 = (const float*)d_in[9];
    const float* b3 = (const float*)d_in[10];
    const int* iidx = (const int*)d_in[11];
    const int* jidx = (const int*)d_in[12];
    const int* sn = (const int*)d_in[13];
    float* out = (float*)d_out;

    float* csn2 = (float*)d_ws;                                  // B*NA*32 f32 = 5.12 MB
    int* starts = (int*)((char*)d_ws + (size_t)B_ * NA_ * NMAX_ * sizeof(float)); // B*(NA+1) ints

    int nthr = B_ * NM_;
    starts_kernel<<<(nthr + 255) / 256, 256, 0, stream>>>(iidx, starts);

    int nblocks = (B_ * NA_ + 3) / 4;  // 4 waves (atoms) per 256-thread block
    pass_kernel<0><<<nblocks, 256, 0, stream>>>(disp, alpha, rsp, spp, op, w1, b1,
                                                w2, b2, w3, b3, jidx, sn, starts,
                                                csn2, out);
    pass_kernel<1><<<nblocks, 256, 0, stream>>>(disp, alpha, rsp, spp, op, w1, b1,
                                                w2, b2, w3, b3, jidx, sn, starts,
                                                csn2, out);
}

// Round 2
// 110.161 us; speedup vs baseline: 1.7214x; 1.7214x over previous
//
#include <hip/hip_runtime.h>
#include <math.h>

#define NA_ 10000
#define NM_ 150000
#define B_  4
#define NS_ 4
#define NMAX_ 32
#define NO_ 4
#define H1_ 4
#define H2_ 38
#define PI_F 3.14159265358979323846f

// ---------------------------------------------------------------------------
// Kernel 0: segment starts from sorted iidx. starts[b][a] = first pair index p
// with iidx[b][p] >= a ; starts[b][NA] = NM.
// ---------------------------------------------------------------------------
__global__ void starts_kernel(const int* __restrict__ iidx, int* __restrict__ starts) {
    int p = blockIdx.x * blockDim.x + threadIdx.x;
    if (p >= B_ * NM_) return;
    int b = p / NM_, pl = p - b * NM_;
    const int* ii = iidx + (size_t)b * NM_;
    int* st = starts + (size_t)b * (NA_ + 1);
    int cur = ii[pl];
    int prev = (pl == 0) ? -1 : ii[pl - 1];
    for (int a = prev + 1; a <= cur; ++a) st[a] = pl;
    if (pl == NM_ - 1) {
        for (int a = cur + 1; a <= NA_; ++a) st[a] = NM_;
    }
}

// ---------------------------------------------------------------------------
// Main pass kernel: one wave = TWO atoms (one per 32-lane half).
// lane: n = lane&31 (radial index), h = lane>>5 selects the atom.
// Each lane holds 4 accumulators acc_l = bnl[atom][l][n], l=0..3.
// PASS=0: density with species_params as Csn, then MLP -> write Csn2.
// PASS=1: density with Csn2, write rho to out.
// ---------------------------------------------------------------------------
template <int PASS>
__global__ __launch_bounds__(256) void pass_kernel(
    const float* __restrict__ disp, const float* __restrict__ alpha,
    const float* __restrict__ rsp, const float* __restrict__ spp,
    const float* __restrict__ op, const float* __restrict__ w1,
    const float* __restrict__ b1, const float* __restrict__ w2,
    const float* __restrict__ b2, const float* __restrict__ w3,
    const float* __restrict__ b3, const int* __restrict__ jidx,
    const int* __restrict__ sorted_numbers, const int* __restrict__ starts,
    float* __restrict__ csn2, float* __restrict__ out)
{
    int wave = blockIdx.x * 4 + (threadIdx.x >> 6);
    int lane = threadIdx.x & 63;
    int h = lane >> 5;
    int n = lane & 31;
    int g = wave * 2 + h;                 // global atom slot (b*NA + a)
    if (g >= B_ * NA_) return;            // never triggers (40000 even), safety
    int b = g / NA_, a = g - b * NA_;

    // per-species per-n tables into registers
    float al[NS_], rv[NS_], spv[NS_];
#pragma unroll
    for (int s = 0; s < NS_; ++s) {
        al[s] = alpha[s * NMAX_ + n];
        rv[s] = rsp[s * NMAX_ + n];
    }
    if constexpr (PASS == 0) {
#pragma unroll
        for (int s = 0; s < NS_; ++s) spv[s] = spp[s * NMAX_ + n];
    }

    // W[l][n][o]: OIDX=[0,1,1,1] -> l=0 uses row0, l=1..3 share row1.
    const float* opb = op + (size_t)PASS * 2 * NMAX_ * NO_;
    float W0[NO_], W1[NO_];
#pragma unroll
    for (int o = 0; o < NO_; ++o) {
        W0[o] = opb[(0 * NMAX_ + n) * NO_ + o];
        W1[o] = opb[(1 * NMAX_ + n) * NO_ + o];
    }

    const int* st = starts + b * (NA_ + 1);
    int p0 = st[a], p1 = st[a + 1];
    const int* jjb = jidx + (size_t)b * NM_;
    const float* dpb = disp + (size_t)b * NM_ * 3;
    const float* csb = csn2 + (size_t)b * NA_ * NMAX_;

    float acc0 = 0.f, acc1 = 0.f, acc2 = 0.f, acc3 = 0.f;

    // ---- software-pipelined pair loop (j 2-deep, rest 1-deep) ----
    int jA = 0, jB = 0;
    float xA = 0.f, yA = 0.f, zA = 0.f;
    int jatA = 0; float cjA = 0.f;
    if (p0 < p1) {
        jA = jjb[p0];
        xA = dpb[p0 * 3 + 0]; yA = dpb[p0 * 3 + 1]; zA = dpb[p0 * 3 + 2];
        jatA = sorted_numbers[jA];
        if constexpr (PASS == 1) cjA = csb[jA * NMAX_ + n];
    }
    if (p0 + 1 < p1) jB = jjb[p0 + 1];

    for (int p = p0; p < p1; ++p) {
        // prefetch stage C (j only) and stage B (deps of jB)
        int jC = 0;
        if (p + 2 < p1) jC = jjb[p + 2];
        int jatB = 0; float cjB = 0.f, xB = 0.f, yB = 0.f, zB = 0.f;
        if (p + 1 < p1) {
            xB = dpb[(p + 1) * 3 + 0];
            yB = dpb[(p + 1) * 3 + 1];
            zB = dpb[(p + 1) * 3 + 2];
            jatB = sorted_numbers[jB];
            if constexpr (PASS == 1) cjB = csb[jB * NMAX_ + n];
        }

        // compute with stage A (all operands already resident)
        float dist = sqrtf(xA * xA + yA * yA + zA * zA);
        float c = __cosf(dist * (PI_F / 6.0f));
        float fcv = 0.25f * (c + 1.f) * (c + 1.f);
        bool s0 = (jatA & 1) != 0, s1 = (jatA & 2) != 0;
        float av  = s1 ? (s0 ? al[3] : al[2]) : (s0 ? al[1] : al[0]);
        float rsv = s1 ? (s0 ? rv[3] : rv[2]) : (s0 ? rv[1] : rv[0]);
        float cj;
        if constexpr (PASS == 0)
            cj = s1 ? (s0 ? spv[3] : spv[2]) : (s0 ? spv[1] : spv[0]);
        else
            cj = cjA;
        float dd = dist - rsv;
        float coef = fcv * cj * __expf(av * dd * dd);
        acc0 += coef;
        acc1 = fmaf(coef, xA, acc1);
        acc2 = fmaf(coef, yA, acc2);
        acc3 = fmaf(coef, zA, acc3);

        // rotate pipeline
        jA = jB; jB = jC;
        xA = xB; yA = yB; zA = zB;
        jatA = jatB; cjA = cjB;
    }

    // ---- t[l][o] = sum_n W[l][n][o] * acc_l : butterfly over the 32-lane half
    float t[4][NO_];
#pragma unroll
    for (int o = 0; o < NO_; ++o) {
        t[0][o] = W0[o] * acc0;
        t[1][o] = W1[o] * acc1;
        t[2][o] = W1[o] * acc2;
        t[3][o] = W1[o] * acc3;
    }
#pragma unroll
    for (int off = 1; off < 32; off <<= 1) {
#pragma unroll
        for (int l = 0; l < 4; ++l)
#pragma unroll
            for (int o = 0; o < NO_; ++o)
                t[l][o] += __shfl_xor(t[l][o], off);
    }
    float rho[NO_];
#pragma unroll
    for (int o = 0; o < NO_; ++o)
        rho[o] = t[0][o] * t[0][o] + t[1][o] * t[1][o] +
                 t[2][o] * t[2][o] + t[3][o] * t[3][o];

    if constexpr (PASS == 1) {
        if (n == 0) {
            *reinterpret_cast<float4*>(out + (size_t)g * NO_) =
                make_float4(rho[0], rho[1], rho[2], rho[3]);
        }
    } else {
        // ---- MLP: rho(4) -> h1(4,tanh) -> h2(38,tanh) -> 32, per atom-half
        float h1v[H1_];
#pragma unroll
        for (int k = 0; k < H1_; ++k) {
            float s = b1[k];
#pragma unroll
            for (int o = 0; o < NO_; ++o) s = fmaf(rho[o], w1[o * H1_ + k], s);
            h1v[k] = tanhf(s);
        }
        // h2[j]: j=n on every lane; j=32+n on lanes n<6 (clamped elsewhere)
        float sa = b2[n];
        int jbi = 32 + (n < 6 ? n : 5);
        float sb = b2[jbi];
#pragma unroll
        for (int k = 0; k < H1_; ++k) {
            sa = fmaf(h1v[k], w2[k * H2_ + n], sa);
            sb = fmaf(h1v[k], w2[k * H2_ + jbi], sb);
        }
        float hva = tanhf(sa);
        float hvb = tanhf(sb);
        // out[n] = b3[n] + sum_j h2[j] * w3[j][n]
        float on = b3[n];
        int base_lane = h << 5;
#pragma unroll
        for (int j2 = 0; j2 < 32; ++j2) {
            float hj = __shfl(hva, base_lane + j2);
            on = fmaf(hj, w3[j2 * NMAX_ + n], on);
        }
#pragma unroll
        for (int j2 = 0; j2 < 6; ++j2) {
            float hj = __shfl(hvb, base_lane + j2);
            on = fmaf(hj, w3[(32 + j2) * NMAX_ + n], on);
        }
        int aat = sorted_numbers[a];
        bool t0b = (aat & 1) != 0, t1b = (aat & 2) != 0;
        float basev = t1b ? (t0b ? spv[3] : spv[2]) : (t0b ? spv[1] : spv[0]);
        csn2[(size_t)g * NMAX_ + n] = basev + on;
    }
}

extern "C" void kernel_launch(void* const* d_in, const int* in_sizes, int n_in,
                              void* d_out, int out_size, void* d_ws, size_t ws_size,
                              hipStream_t stream) {
    const float* disp = (const float*)d_in[0];
    const float* alpha = (const float*)d_in[1];
    const float* rsp = (const float*)d_in[2];
    const float* spp = (const float*)d_in[3];
    const float* op = (const float*)d_in[4];
    const float* w1 = (const float*)d_in[5];
    const float* b1 = (const float*)d_in[6];
    const float* w2 = (const float*)d_in[7];
    const float* b2 = (const float*)d_in[8];
    const float* w3 = (const float*)d_in[9];
    const float* b3 = (const float*)d_in[10];
    const int* iidx = (const int*)d_in[11];
    const int* jidx = (const int*)d_in[12];
    const int* sn = (const int*)d_in[13];
    float* out = (float*)d_out;

    float* csn2 = (float*)d_ws;                                  // B*NA*32 f32 = 5.12 MB
    int* starts = (int*)((char*)d_ws + (size_t)B_ * NA_ * NMAX_ * sizeof(float));

    int nthr = B_ * NM_;
    starts_kernel<<<(nthr + 255) / 256, 256, 0, stream>>>(iidx, starts);

    int nwaves = (B_ * NA_) / 2;               // 2 atoms per wave
    int nblocks = (nwaves + 3) / 4;            // 4 waves per 256-thread block
    pass_kernel<0><<<nblocks, 256, 0, stream>>>(disp, alpha, rsp, spp, op, w1, b1,
                                                w2, b2, w3, b3, jidx, sn, starts,
                                                csn2, out);
    pass_kernel<1><<<nblocks, 256, 0, stream>>>(disp, alpha, rsp, spp, op, w1, b1,
                                                w2, b2, w3, b3, jidx, sn, starts,
                                                csn2, out);
}